// Round 1
// baseline (639.593 us; speedup 1.0000x reference)
//
#include <hip/hip_runtime.h>
#include <stdint.h>

#define M_DIM 8192
#define K_DIM 4096
#define N_DIM 4096

using f32x4 = __attribute__((ext_vector_type(4))) float;
typedef long i64;

// ---------- fp8 e4m3 packing (HW RNE conversion; inputs pre-clipped to +-448) ----------
__device__ inline uint32_t pk_fp8_x4(float a, float b, float c, float d) {
    int lo   = __builtin_amdgcn_cvt_pk_fp8_f32(a, b, 0, false);   // bytes 0,1
    int both = __builtin_amdgcn_cvt_pk_fp8_f32(c, d, lo, true);   // bytes 2,3
    return (uint32_t)both;
}

__device__ inline float clip448(float v) {
    return fminf(fmaxf(v, -448.0f), 448.0f);
}

__device__ inline void gload_lds16(const void* g, void* l) {
    __builtin_amdgcn_global_load_lds(
        (const __attribute__((address_space(1))) uint32_t*)g,
        (__attribute__((address_space(3))) uint32_t*)l, 16, 0, 0);
}

// ---------- init amax accumulators ----------
__global__ void init_amax(float* a) {
    if (threadIdx.x < 2) a[threadIdx.x] = 0.0f;
}

// ---------- quantize x: f32 [M][K] -> e4m3 [M][K], fused amax ----------
__global__ void quant_x_kernel(const float* __restrict__ x, uint8_t* __restrict__ qx,
                               const float* __restrict__ scale_p, float* __restrict__ amax_out,
                               int n4) {
    const float scale = scale_p[0];
    float lmax = 0.0f;
    const float4* xv = (const float4*)x;
    uint32_t* qv = (uint32_t*)qx;
    int stride = gridDim.x * blockDim.x;
    for (int i = blockIdx.x * blockDim.x + threadIdx.x; i < n4; i += stride) {
        float4 v = xv[i];
        lmax = fmaxf(lmax, fmaxf(fmaxf(fabsf(v.x), fabsf(v.y)),
                                 fmaxf(fabsf(v.z), fabsf(v.w))));
        float a = clip448(v.x / scale);
        float b = clip448(v.y / scale);
        float c = clip448(v.z / scale);
        float d = clip448(v.w / scale);
        qv[i] = pk_fp8_x4(a, b, c, d);
    }
    #pragma unroll
    for (int off = 32; off; off >>= 1) lmax = fmaxf(lmax, __shfl_xor(lmax, off));
    if ((threadIdx.x & 63) == 0) atomicMax((int*)amax_out, __float_as_int(lmax));
}

// ---------- quantize kernel transposed: f32 [K][N] -> e4m3 [N][K], fused amax ----------
__global__ void quant_kT_kernel(const float* __restrict__ kin, uint8_t* __restrict__ qkT,
                                const float* __restrict__ scale_p, float* __restrict__ amax_out) {
    __shared__ uint8_t sm[64 * 68];  // [k 0..63][n 0..63], pad 68 to kill bank conflicts
    const float scale = scale_p[0];
    const int t = threadIdx.x;
    const int bk = blockIdx.x & 63;   // K-tile index (64 tiles)
    const int bn = blockIdx.x >> 6;   // N-tile index (64 tiles)
    const int gk0 = bk * 64, gn0 = bn * 64;
    float lmax = 0.0f;

    #pragma unroll
    for (int it = 0; it < 4; ++it) {
        int k  = it * 16 + (t >> 4);
        int n4 = (t & 15) * 4;
        float4 v = *(const float4*)(kin + (size_t)(gk0 + k) * N_DIM + gn0 + n4);
        lmax = fmaxf(lmax, fmaxf(fmaxf(fabsf(v.x), fabsf(v.y)),
                                 fmaxf(fabsf(v.z), fabsf(v.w))));
        float a = clip448(v.x / scale);
        float b = clip448(v.y / scale);
        float c = clip448(v.z / scale);
        float d = clip448(v.w / scale);
        *(uint32_t*)(sm + k * 68 + n4) = pk_fp8_x4(a, b, c, d);
    }
    __syncthreads();
    #pragma unroll
    for (int it = 0; it < 4; ++it) {
        int n  = it * 16 + (t >> 4);
        int k4 = (t & 15) * 4;
        uint32_t w = (uint32_t)sm[(k4 + 0) * 68 + n]
                   | ((uint32_t)sm[(k4 + 1) * 68 + n] << 8)
                   | ((uint32_t)sm[(k4 + 2) * 68 + n] << 16)
                   | ((uint32_t)sm[(k4 + 3) * 68 + n] << 24);
        *(uint32_t*)(qkT + (size_t)(gn0 + n) * K_DIM + gk0 + k4) = w;
    }
    #pragma unroll
    for (int off = 32; off; off >>= 1) lmax = fmaxf(lmax, __shfl_xor(lmax, off));
    if ((threadIdx.x & 63) == 0) atomicMax((int*)amax_out, __float_as_int(lmax));
}

// ---------- fp8 GEMM: C[M][N] = (sA*sB) * qx[M][K] . qkT[N][K]^T + bias ----------
// 128x128 tile, BK=64 bytes, 4 waves (2x2), 16x16x32 fp8 MFMA.
// LDS layout per operand: [ks][row 0..127][32 bytes]  (k-half-major -> 2-way banks = free)
__global__ __launch_bounds__(256) void gemm_fp8(
        const uint8_t* __restrict__ A,   // [M][K] e4m3
        const uint8_t* __restrict__ Bt,  // [N][K] e4m3
        const float* __restrict__ bias,
        const float* __restrict__ sIn, const float* __restrict__ sK,
        float* __restrict__ C) {
    __shared__ uint8_t smA[8192];
    __shared__ uint8_t smB[8192];

    const int nwg = gridDim.x;              // 2048, divisible by 8
    const int cpx = nwg >> 3;
    const int swz = (blockIdx.x & 7) * cpx + (blockIdx.x >> 3);
    const int ntiles = N_DIM / 128;         // 32
    const int mt = swz / ntiles, nt = swz % ntiles;
    const int gRow0 = mt * 128, gCol0 = nt * 128;

    const int tid = threadIdx.x;
    const int lane = tid & 63, wid = tid >> 6;
    const int wm = wid >> 1, wn = wid & 1;
    const int r = lane & 15, g = lane >> 4;

    f32x4 acc[4][4] = {};

    // staging addresses: idx = c*256 + tid; LDS linear idx*16
    // target layout: lds_off = ks*4096 + row*32 + half*16
    //   idx bit0 = half, bits1..7 = row, bit8 = ks
    const uint8_t* gA[2];
    const uint8_t* gB[2];
    #pragma unroll
    for (int c = 0; c < 2; ++c) {
        int idx  = c * 256 + tid;
        int half = idx & 1;
        int row  = (idx >> 1) & 127;
        int ks   = idx >> 8;
        gA[c] = A  + (size_t)(gRow0 + row) * K_DIM + ks * 32 + half * 16;
        gB[c] = Bt + (size_t)(gCol0 + row) * K_DIM + ks * 32 + half * 16;
    }

    for (int kt = 0; kt < K_DIM / 64; ++kt) {
        const int k0 = kt * 64;
        #pragma unroll
        for (int c = 0; c < 2; ++c) {
            int idx = c * 256 + tid;
            gload_lds16(gA[c] + k0, smA + idx * 16);
            gload_lds16(gB[c] + k0, smB + idx * 16);
        }
        __syncthreads();

        #pragma unroll
        for (int ks = 0; ks < 2; ++ks) {
            i64 af[4], bf[4];
            #pragma unroll
            for (int m = 0; m < 4; ++m)
                af[m] = *(const i64*)(smA + ks * 4096 + (wm * 64 + m * 16 + r) * 32 + g * 8);
            #pragma unroll
            for (int n = 0; n < 4; ++n)
                bf[n] = *(const i64*)(smB + ks * 4096 + (wn * 64 + n * 16 + r) * 32 + g * 8);
            #pragma unroll
            for (int m = 0; m < 4; ++m)
                #pragma unroll
                for (int n = 0; n < 4; ++n)
                    acc[m][n] = __builtin_amdgcn_mfma_f32_16x16x32_fp8_fp8(
                        af[m], bf[n], acc[m][n], 0, 0, 0);
        }
        __syncthreads();
    }

    const float s = sIn[0] * sK[0];
    #pragma unroll
    for (int n = 0; n < 4; ++n) {
        const int col = gCol0 + wn * 64 + n * 16 + r;
        const float bv = bias[col];
        #pragma unroll
        for (int m = 0; m < 4; ++m) {
            const int row0 = gRow0 + wm * 64 + m * 16 + g * 4;
            #pragma unroll
            for (int reg = 0; reg < 4; ++reg)
                C[(size_t)(row0 + reg) * N_DIM + col] = acc[m][n][reg] * s + bv;
        }
    }
}

// ---------- rolling-amax state update ----------
__global__ void state_kernel(const float* __restrict__ amax2,
                             const float* __restrict__ inHist,
                             const float* __restrict__ kHist,
                             float* __restrict__ tail) {
    if (threadIdx.x == 0) {
        #pragma unroll
        for (int which = 0; which < 2; ++which) {
            const float* h = which ? kHist : inHist;
            float ac = amax2[which];
            float m = 0.0009765625f;  // 2^-10
            m = fmaxf(m, ac);
            tail[2 + which * 16 + 0] = ac;
            for (int i = 1; i < 16; ++i) {
                float v = h[i - 1];
                tail[2 + which * 16 + i] = v;
                m = fmaxf(m, v);
            }
            tail[which] = 1.1f * m / 448.0f;
        }
    }
}

extern "C" void kernel_launch(void* const* d_in, const int* in_sizes, int n_in,
                              void* d_out, int out_size, void* d_ws, size_t ws_size,
                              hipStream_t stream) {
    const float* x        = (const float*)d_in[0];
    const float* kern     = (const float*)d_in[1];
    const float* bias     = (const float*)d_in[2];
    const float* in_scale = (const float*)d_in[3];
    const float* k_scale  = (const float*)d_in[4];
    const float* in_hist  = (const float*)d_in[7];
    const float* k_hist   = (const float*)d_in[8];

    const size_t qx_bytes  = (size_t)M_DIM * K_DIM;       // 32 MiB
    const size_t qkT_bytes = (size_t)K_DIM * N_DIM;       // 16 MiB
    if (ws_size < qx_bytes + qkT_bytes + 2 * sizeof(float)) return;  // fail visibly, no corruption

    uint8_t* qx   = (uint8_t*)d_ws;
    uint8_t* qkT  = qx + qx_bytes;
    float*   amax2 = (float*)(qkT + qkT_bytes);
    float*   out  = (float*)d_out;

    init_amax<<<1, 64, 0, stream>>>(amax2);
    quant_x_kernel<<<2048, 256, 0, stream>>>(x, qx, in_scale, amax2 + 0,
                                             (int)((size_t)M_DIM * K_DIM / 4));
    quant_kT_kernel<<<64 * 64, 256, 0, stream>>>(kern, qkT, k_scale, amax2 + 1);
    gemm_fp8<<<(M_DIM / 128) * (N_DIM / 128), 256, 0, stream>>>(qx, qkT, bias,
                                                                in_scale, k_scale, out);
    state_kernel<<<1, 64, 0, stream>>>(amax2, in_hist, k_hist,
                                       out + (size_t)M_DIM * N_DIM);
}

// Round 2
// 305.608 us; speedup vs baseline: 2.0929x; 2.0929x over previous
//
#include <hip/hip_runtime.h>
#include <stdint.h>

#define M_DIM 8192
#define K_DIM 4096
#define N_DIM 4096

using f32x4 = __attribute__((ext_vector_type(4))) float;
using i64x2 = __attribute__((ext_vector_type(2))) long;
typedef long i64;

// ---------- fp8 e4m3 packing (HW RNE conversion; inputs pre-clipped to +-448) ----------
__device__ inline uint32_t pk_fp8_x4(float a, float b, float c, float d) {
    int lo   = __builtin_amdgcn_cvt_pk_fp8_f32(a, b, 0, false);   // bytes 0,1
    int both = __builtin_amdgcn_cvt_pk_fp8_f32(c, d, lo, true);   // bytes 2,3
    return (uint32_t)both;
}

__device__ inline float clip448(float v) {
    return fminf(fmaxf(v, -448.0f), 448.0f);
}

__device__ inline void gload_lds16(const void* g, void* l) {
    __builtin_amdgcn_global_load_lds(
        (const __attribute__((address_space(1))) uint32_t*)g,
        (__attribute__((address_space(3))) uint32_t*)l, 16, 0, 0);
}

// K-permutation within each 64-byte K-block:
// orig k = b*64 + ks*32 + g*8 + j  ->  stored p = b*64 + g*16 + ks*8 + j
// This makes a GEMM lane's (ks=0, ks=1) fragments adjacent -> single ds_read_b128.

// ---------- quantize x: f32 [M][K] -> e4m3 [M][K] (K-permuted), per-block amax ----------
__global__ void quant_x_kernel(const float* __restrict__ x, uint8_t* __restrict__ qx,
                               const float* __restrict__ scale_p, float* __restrict__ bm,
                               int n8) {
    __shared__ float red[4];
    const float inv = 1.0f / scale_p[0];
    float lmax = 0.0f;
    const float4* xv = (const float4*)x;
    const int stride = gridDim.x * blockDim.x;
    for (int u = blockIdx.x * blockDim.x + threadIdx.x; u < n8; u += stride) {
        float4 v0 = xv[2 * u];
        float4 v1 = xv[2 * u + 1];
        lmax = fmaxf(lmax, fmaxf(fmaxf(fabsf(v0.x), fabsf(v0.y)),
                                 fmaxf(fabsf(v0.z), fabsf(v0.w))));
        lmax = fmaxf(lmax, fmaxf(fmaxf(fabsf(v1.x), fabsf(v1.y)),
                                 fmaxf(fabsf(v1.z), fabsf(v1.w))));
        uint32_t w0 = pk_fp8_x4(clip448(v0.x * inv), clip448(v0.y * inv),
                                clip448(v0.z * inv), clip448(v0.w * inv));
        uint32_t w1 = pk_fp8_x4(clip448(v1.x * inv), clip448(v1.y * inv),
                                clip448(v1.z * inv), clip448(v1.w * inv));
        // permuted 8B destination
        size_t b  = (size_t)(u >> 3);
        int   wo  = u & 7;              // orig unit = ks*4 + g
        int   ks  = wo >> 2, g = wo & 3;
        uint2* dst = (uint2*)(qx + b * 64 + g * 16 + ks * 8);
        *dst = make_uint2(w0, w1);
    }
    #pragma unroll
    for (int off = 32; off; off >>= 1) lmax = fmaxf(lmax, __shfl_xor(lmax, off));
    if ((threadIdx.x & 63) == 0) red[threadIdx.x >> 6] = lmax;
    __syncthreads();
    if (threadIdx.x == 0)
        bm[blockIdx.x] = fmaxf(fmaxf(red[0], red[1]), fmaxf(red[2], red[3]));
}

// ---------- quantize kernel transposed: f32 [K][N] -> e4m3 [N][K] (K-permuted) ----------
__global__ void quant_kT_kernel(const float* __restrict__ kin, uint8_t* __restrict__ qkT,
                                const float* __restrict__ scale_p, float* __restrict__ bm) {
    __shared__ uint8_t sm[64 * 68];  // [k 0..63][n 0..63], pad 68
    __shared__ float red[4];
    const float inv = 1.0f / scale_p[0];
    const int t = threadIdx.x;
    const int bk = blockIdx.x & 63;   // K-tile index (64 tiles)
    const int bn = blockIdx.x >> 6;   // N-tile index (64 tiles)
    const int gk0 = bk * 64, gn0 = bn * 64;
    float lmax = 0.0f;

    #pragma unroll
    for (int it = 0; it < 4; ++it) {
        int k  = it * 16 + (t >> 4);
        int n4 = (t & 15) * 4;
        float4 v = *(const float4*)(kin + (size_t)(gk0 + k) * N_DIM + gn0 + n4);
        lmax = fmaxf(lmax, fmaxf(fmaxf(fabsf(v.x), fabsf(v.y)),
                                 fmaxf(fabsf(v.z), fabsf(v.w))));
        *(uint32_t*)(sm + k * 68 + n4) = pk_fp8_x4(clip448(v.x * inv), clip448(v.y * inv),
                                                   clip448(v.z * inv), clip448(v.w * inv));
    }
    __syncthreads();
    #pragma unroll
    for (int it = 0; it < 4; ++it) {
        int n  = it * 16 + (t >> 4);
        int k4 = (t & 15) * 4;                  // 0..60, multiple of 4
        uint32_t w = (uint32_t)sm[(k4 + 0) * 68 + n]
                   | ((uint32_t)sm[(k4 + 1) * 68 + n] << 8)
                   | ((uint32_t)sm[(k4 + 2) * 68 + n] << 16)
                   | ((uint32_t)sm[(k4 + 3) * 68 + n] << 24);
        int ks = k4 >> 5, g = (k4 >> 3) & 3, j = k4 & 4;
        int p  = g * 16 + ks * 8 + j;           // permuted word position in 64B block
        *(uint32_t*)(qkT + (size_t)(gn0 + n) * K_DIM + gk0 + p) = w;
    }
    #pragma unroll
    for (int off = 32; off; off >>= 1) lmax = fmaxf(lmax, __shfl_xor(lmax, off));
    if ((t & 63) == 0) red[t >> 6] = lmax;
    __syncthreads();
    if (t == 0)
        bm[blockIdx.x] = fmaxf(fmaxf(red[0], red[1]), fmaxf(red[2], red[3]));
}

// ---------- fp8 GEMM: C[M][N] = (sA*sB) * qx[M][K] . qkT[N][K]^T + bias ----------
// 128x128 tile, BK=64 bytes, 4 waves (2x2), 16x16x32 fp8 MFMA.
// LDS layout per operand: [row 0..127][64B permuted K-block] -> ds_read_b128 at row*64+g*16
// (same bank pattern as the verified m97/m145 structure).
__global__ __launch_bounds__(256) void gemm_fp8(
        const uint8_t* __restrict__ A,   // [M][K] e4m3, K-permuted
        const uint8_t* __restrict__ Bt,  // [N][K] e4m3, K-permuted
        const float* __restrict__ bias,
        const float* __restrict__ sIn, const float* __restrict__ sK,
        float* __restrict__ C) {
    __shared__ uint8_t smA[8192];
    __shared__ uint8_t smB[8192];

    const int nwg = gridDim.x;              // 2048, divisible by 8
    const int cpx = nwg >> 3;
    const int swz = (blockIdx.x & 7) * cpx + (blockIdx.x >> 3);
    const int ntiles = N_DIM / 128;         // 32
    const int mt = swz / ntiles, nt = swz % ntiles;
    const int gRow0 = mt * 128, gCol0 = nt * 128;

    const int tid = threadIdx.x;
    const int lane = tid & 63, wid = tid >> 6;
    const int wm = wid >> 1, wn = wid & 1;
    const int r = lane & 15, g = lane >> 4;

    f32x4 acc[4][4] = {};

    // staging: idx = c*256 + tid; LDS byte idx*16; row = idx>>2, poff = (idx&3)*16
    const uint8_t* gA[2];
    const uint8_t* gB[2];
    #pragma unroll
    for (int c = 0; c < 2; ++c) {
        int idx  = c * 256 + tid;
        int row  = idx >> 2;
        int poff = (idx & 3) * 16;
        gA[c] = A  + (size_t)(gRow0 + row) * K_DIM + poff;
        gB[c] = Bt + (size_t)(gCol0 + row) * K_DIM + poff;
    }

    for (int kt = 0; kt < K_DIM / 64; ++kt) {
        const int k0 = kt * 64;
        #pragma unroll
        for (int c = 0; c < 2; ++c) {
            int idx = c * 256 + tid;
            gload_lds16(gA[c] + k0, smA + idx * 16);
            gload_lds16(gB[c] + k0, smB + idx * 16);
        }
        __syncthreads();

        i64x2 a2[4], b2[4];
        #pragma unroll
        for (int m = 0; m < 4; ++m)
            a2[m] = *(const i64x2*)(smA + (wm * 64 + m * 16 + r) * 64 + g * 16);
        #pragma unroll
        for (int n = 0; n < 4; ++n)
            b2[n] = *(const i64x2*)(smB + (wn * 64 + n * 16 + r) * 64 + g * 16);

        #pragma unroll
        for (int ks = 0; ks < 2; ++ks)
            #pragma unroll
            for (int m = 0; m < 4; ++m)
                #pragma unroll
                for (int n = 0; n < 4; ++n)
                    acc[m][n] = __builtin_amdgcn_mfma_f32_16x16x32_fp8_fp8(
                        a2[m][ks], b2[n][ks], acc[m][n], 0, 0, 0);
        __syncthreads();
    }

    const float s = sIn[0] * sK[0];
    #pragma unroll
    for (int n = 0; n < 4; ++n) {
        const int col = gCol0 + wn * 64 + n * 16 + r;
        const float bv = bias[col];
        #pragma unroll
        for (int m = 0; m < 4; ++m) {
            const int row0 = gRow0 + wm * 64 + m * 16 + g * 4;
            #pragma unroll
            for (int reg = 0; reg < 4; ++reg)
                C[(size_t)(row0 + reg) * N_DIM + col] = acc[m][n][reg] * s + bv;
        }
    }
}

// ---------- reduce block maxes + rolling-amax state update ----------
__global__ void state_kernel(const float* __restrict__ bmx, int nx,
                             const float* __restrict__ bmk, int nk,
                             const float* __restrict__ inHist,
                             const float* __restrict__ kHist,
                             float* __restrict__ tail) {
    __shared__ float red[8];
    const int t = threadIdx.x;
    float mx = 0.0f, mk = 0.0f;
    for (int i = t; i < nx; i += 256) mx = fmaxf(mx, bmx[i]);
    for (int i = t; i < nk; i += 256) mk = fmaxf(mk, bmk[i]);
    #pragma unroll
    for (int off = 32; off; off >>= 1) {
        mx = fmaxf(mx, __shfl_xor(mx, off));
        mk = fmaxf(mk, __shfl_xor(mk, off));
    }
    if ((t & 63) == 0) { red[t >> 6] = mx; red[4 + (t >> 6)] = mk; }
    __syncthreads();
    if (t == 0) {
        float amax_x = fmaxf(fmaxf(red[0], red[1]), fmaxf(red[2], red[3]));
        float amax_k = fmaxf(fmaxf(red[4], red[5]), fmaxf(red[6], red[7]));
        #pragma unroll
        for (int which = 0; which < 2; ++which) {
            const float* h = which ? kHist : inHist;
            float ac = which ? amax_k : amax_x;
            float m = fmaxf(0.0009765625f, ac);   // 2^-10
            tail[2 + which * 16 + 0] = ac;
            for (int i = 1; i < 16; ++i) {
                float v = h[i - 1];
                tail[2 + which * 16 + i] = v;
                m = fmaxf(m, v);
            }
            tail[which] = 1.1f * m / 448.0f;
        }
    }
}

extern "C" void kernel_launch(void* const* d_in, const int* in_sizes, int n_in,
                              void* d_out, int out_size, void* d_ws, size_t ws_size,
                              hipStream_t stream) {
    const float* x        = (const float*)d_in[0];
    const float* kern     = (const float*)d_in[1];
    const float* bias     = (const float*)d_in[2];
    const float* in_scale = (const float*)d_in[3];
    const float* k_scale  = (const float*)d_in[4];
    const float* in_hist  = (const float*)d_in[7];
    const float* k_hist   = (const float*)d_in[8];

    const int NBX = 2048;              // quant_x blocks
    const int NBK = 64 * 64;           // quant_kT blocks
    const size_t qx_bytes  = (size_t)M_DIM * K_DIM;       // 32 MiB
    const size_t qkT_bytes = (size_t)K_DIM * N_DIM;       // 16 MiB
    const size_t need = qx_bytes + qkT_bytes + (NBX + NBK) * sizeof(float);
    if (ws_size < need) return;  // fail visibly, no corruption

    uint8_t* qx  = (uint8_t*)d_ws;
    uint8_t* qkT = qx + qx_bytes;
    float*   bmx = (float*)(qkT + qkT_bytes);
    float*   bmk = bmx + NBX;
    float*   out = (float*)d_out;

    quant_x_kernel<<<NBX, 256, 0, stream>>>(x, qx, in_scale, bmx,
                                            (int)((size_t)M_DIM * K_DIM / 8));
    quant_kT_kernel<<<NBK, 256, 0, stream>>>(kern, qkT, k_scale, bmk);
    gemm_fp8<<<(M_DIM / 128) * (N_DIM / 128), 256, 0, stream>>>(qx, qkT, bias,
                                                                in_scale, k_scale, out);
    state_kernel<<<1, 256, 0, stream>>>(bmx, NBX, bmk, NBK, in_hist, k_hist,
                                        out + (size_t)M_DIM * N_DIM);
}

// Round 3
// 223.968 us; speedup vs baseline: 2.8557x; 1.3645x over previous
//
#include <hip/hip_runtime.h>
#include <stdint.h>

#define M_DIM 8192
#define K_DIM 4096
#define N_DIM 4096

using f32x4 = __attribute__((ext_vector_type(4))) float;
using i32x4 = __attribute__((ext_vector_type(4))) int;
using i32x8 = __attribute__((ext_vector_type(8))) int;

#define UNIT_SCALE 0x7F7F7F7F   // 4x E8M0 exponent-127 bytes -> 2^0

// ---------- fp8 e4m3 packing (HW RNE conversion; inputs pre-clipped to +-448) ----------
__device__ inline uint32_t pk_fp8_x4(float a, float b, float c, float d) {
    int lo   = __builtin_amdgcn_cvt_pk_fp8_f32(a, b, 0, false);   // bytes 0,1
    int both = __builtin_amdgcn_cvt_pk_fp8_f32(c, d, lo, true);   // bytes 2,3
    return (uint32_t)both;
}

__device__ inline float clip448(float v) {
    return fminf(fmaxf(v, -448.0f), 448.0f);
}

__device__ inline void gload_lds16(const void* g, void* l) {
    __builtin_amdgcn_global_load_lds(
        (const __attribute__((address_space(1))) uint32_t*)g,
        (__attribute__((address_space(3))) uint32_t*)l, 16, 0, 0);
}

// K-permutation within each 128-byte K-block (for 16x16x128 scaled MFMA):
// orig k (c = k>>5, g = (k>>3)&3, j = k&7)  ->  stored p = g*32 + c*8 + j
// => a GEMM lane (g = lane>>4) reads its 32-byte fragment contiguously at p = g*32.

// ---------- quantize x: f32 [M][K] -> e4m3 [M][K] (K-permuted), per-block amax ----------
__global__ void quant_x_kernel(const float* __restrict__ x, uint8_t* __restrict__ qx,
                               const float* __restrict__ scale_p, float* __restrict__ bm,
                               int n8) {
    __shared__ float red[4];
    const float inv = 1.0f / scale_p[0];
    float lmax = 0.0f;
    const float4* xv = (const float4*)x;
    const int stride = gridDim.x * blockDim.x;
    for (int u = blockIdx.x * blockDim.x + threadIdx.x; u < n8; u += stride) {
        float4 v0 = xv[2 * u];
        float4 v1 = xv[2 * u + 1];
        lmax = fmaxf(lmax, fmaxf(fmaxf(fabsf(v0.x), fabsf(v0.y)),
                                 fmaxf(fabsf(v0.z), fabsf(v0.w))));
        lmax = fmaxf(lmax, fmaxf(fmaxf(fabsf(v1.x), fabsf(v1.y)),
                                 fmaxf(fabsf(v1.z), fabsf(v1.w))));
        uint32_t w0 = pk_fp8_x4(clip448(v0.x * inv), clip448(v0.y * inv),
                                clip448(v0.z * inv), clip448(v0.w * inv));
        uint32_t w1 = pk_fp8_x4(clip448(v1.x * inv), clip448(v1.y * inv),
                                clip448(v1.z * inv), clip448(v1.w * inv));
        // permuted 8B destination within 128B block
        size_t b  = (size_t)(u >> 4);   // 128-byte block
        int   u8  = u & 15;             // orig 8B unit = c*4 + g
        int   c   = u8 >> 2, g = u8 & 3;
        uint2* dst = (uint2*)(qx + b * 128 + (size_t)(g * 4 + c) * 8);
        *dst = make_uint2(w0, w1);
    }
    #pragma unroll
    for (int off = 32; off; off >>= 1) lmax = fmaxf(lmax, __shfl_xor(lmax, off));
    if ((threadIdx.x & 63) == 0) red[threadIdx.x >> 6] = lmax;
    __syncthreads();
    if (threadIdx.x == 0)
        bm[blockIdx.x] = fmaxf(fmaxf(red[0], red[1]), fmaxf(red[2], red[3]));
}

// ---------- quantize kernel transposed: f32 [K][N] -> e4m3 [N][K] (K-permuted) ----------
__global__ void quant_kT_kernel(const float* __restrict__ kin, uint8_t* __restrict__ qkT,
                                const float* __restrict__ scale_p, float* __restrict__ bm) {
    __shared__ uint8_t sm[64 * 68];  // [k 0..63][n 0..63], pad 68
    __shared__ float red[4];
    const float inv = 1.0f / scale_p[0];
    const int t = threadIdx.x;
    const int bk = blockIdx.x & 63;   // K-tile index (64 tiles)
    const int bn = blockIdx.x >> 6;   // N-tile index (64 tiles)
    const int gk0 = bk * 64, gn0 = bn * 64;
    float lmax = 0.0f;

    #pragma unroll
    for (int it = 0; it < 4; ++it) {
        int k  = it * 16 + (t >> 4);
        int n4 = (t & 15) * 4;
        float4 v = *(const float4*)(kin + (size_t)(gk0 + k) * N_DIM + gn0 + n4);
        lmax = fmaxf(lmax, fmaxf(fmaxf(fabsf(v.x), fabsf(v.y)),
                                 fmaxf(fabsf(v.z), fabsf(v.w))));
        *(uint32_t*)(sm + k * 68 + n4) = pk_fp8_x4(clip448(v.x * inv), clip448(v.y * inv),
                                                   clip448(v.z * inv), clip448(v.w * inv));
    }
    __syncthreads();
    #pragma unroll
    for (int it = 0; it < 4; ++it) {
        int n  = it * 16 + (t >> 4);
        int k4 = (t & 15) * 4;                  // 0..60, multiple of 4
        uint32_t w = (uint32_t)sm[(k4 + 0) * 68 + n]
                   | ((uint32_t)sm[(k4 + 1) * 68 + n] << 8)
                   | ((uint32_t)sm[(k4 + 2) * 68 + n] << 16)
                   | ((uint32_t)sm[(k4 + 3) * 68 + n] << 24);
        int kk = (gk0 + k4);
        size_t b = (size_t)(kk >> 7);           // 128-byte block
        int  kp  = kk & 127;
        int  c   = kp >> 5, g = (kp >> 3) & 3, j = kp & 7;   // j in {0,4}
        int  p   = g * 32 + c * 8 + j;
        *(uint32_t*)(qkT + (size_t)(gn0 + n) * K_DIM + b * 128 + p) = w;
    }
    #pragma unroll
    for (int off = 32; off; off >>= 1) lmax = fmaxf(lmax, __shfl_xor(lmax, off));
    if ((t & 63) == 0) red[t >> 6] = lmax;
    __syncthreads();
    if (t == 0)
        bm[blockIdx.x] = fmaxf(fmaxf(red[0], red[1]), fmaxf(red[2], red[3]));
}

// ---------- MX-fp8 GEMM (unit scales): C = (sA*sB) * qx . qkT^T + bias ----------
// 128x128 tile, BK=128 bytes, 4 waves (2x2), mfma_scale_f32_16x16x128_f8f6f4.
// LDS [row][128B], 16B units XOR-swizzled by (row&7) -> 2-way banks (free).
// Swizzle applied on the GLOBAL source address (gload_lds dest stays linear, rule #21).
__global__ __launch_bounds__(256) void gemm_mx(
        const uint8_t* __restrict__ A,   // [M][K] e4m3, K-permuted per 128B block
        const uint8_t* __restrict__ Bt,  // [N][K] e4m3, K-permuted per 128B block
        const float* __restrict__ bias,
        const float* __restrict__ sIn, const float* __restrict__ sK,
        float* __restrict__ C) {
    __shared__ uint8_t smA[16384];
    __shared__ uint8_t smB[16384];

    const int nwg = gridDim.x;              // 2048, divisible by 8
    const int cpx = nwg >> 3;
    const int swz = (blockIdx.x & 7) * cpx + (blockIdx.x >> 3);
    const int ntiles = N_DIM / 128;         // 32
    const int mt = swz / ntiles, nt = swz % ntiles;
    const int gRow0 = mt * 128, gCol0 = nt * 128;

    const int tid = threadIdx.x;
    const int lane = tid & 63, wid = tid >> 6;
    const int wm = wid >> 1, wn = wid & 1;
    const int r = lane & 15, g = lane >> 4;

    f32x4 acc[4][4] = {};

    // staging: idx = c*256 + tid; LDS byte idx*16 (linear).
    // physical 16B unit pu = idx&7 holds logical unit lu = pu ^ (row&7).
    const uint8_t* gA[4];
    const uint8_t* gB[4];
    #pragma unroll
    for (int c = 0; c < 4; ++c) {
        int idx = c * 256 + tid;
        int row = idx >> 3;
        int lu  = (idx & 7) ^ (row & 7);
        gA[c] = A  + (size_t)(gRow0 + row) * K_DIM + lu * 16;
        gB[c] = Bt + (size_t)(gCol0 + row) * K_DIM + lu * 16;
    }

    for (int kt = 0; kt < K_DIM / 128; ++kt) {
        const int k0 = kt * 128;
        #pragma unroll
        for (int c = 0; c < 4; ++c) {
            int idx = c * 256 + tid;
            gload_lds16(gA[c] + k0, smA + idx * 16);
            gload_lds16(gB[c] + k0, smB + idx * 16);
        }
        __syncthreads();

        i32x8 af[4], bf[4];
        #pragma unroll
        for (int m = 0; m < 4; ++m) {
            int row = wm * 64 + m * 16 + r;
            int s   = row & 7;
            i32x4 lo = *(const i32x4*)(smA + row * 128 + (((g * 2 + 0) ^ s) * 16));
            i32x4 hi = *(const i32x4*)(smA + row * 128 + (((g * 2 + 1) ^ s) * 16));
            af[m][0] = lo[0]; af[m][1] = lo[1]; af[m][2] = lo[2]; af[m][3] = lo[3];
            af[m][4] = hi[0]; af[m][5] = hi[1]; af[m][6] = hi[2]; af[m][7] = hi[3];
        }
        #pragma unroll
        for (int n = 0; n < 4; ++n) {
            int row = wn * 64 + n * 16 + r;
            int s   = row & 7;
            i32x4 lo = *(const i32x4*)(smB + row * 128 + (((g * 2 + 0) ^ s) * 16));
            i32x4 hi = *(const i32x4*)(smB + row * 128 + (((g * 2 + 1) ^ s) * 16));
            bf[n][0] = lo[0]; bf[n][1] = lo[1]; bf[n][2] = lo[2]; bf[n][3] = lo[3];
            bf[n][4] = hi[0]; bf[n][5] = hi[1]; bf[n][6] = hi[2]; bf[n][7] = hi[3];
        }

        #pragma unroll
        for (int m = 0; m < 4; ++m)
            #pragma unroll
            for (int n = 0; n < 4; ++n)
                acc[m][n] = __builtin_amdgcn_mfma_scale_f32_16x16x128_f8f6f4(
                    af[m], bf[n], acc[m][n], 0, 0,
                    0, UNIT_SCALE, 0, UNIT_SCALE);
        __syncthreads();
    }

    const float s = sIn[0] * sK[0];
    #pragma unroll
    for (int n = 0; n < 4; ++n) {
        const int col = gCol0 + wn * 64 + n * 16 + r;
        const float bv = bias[col];
        #pragma unroll
        for (int m = 0; m < 4; ++m) {
            const int row0 = gRow0 + wm * 64 + m * 16 + g * 4;
            #pragma unroll
            for (int reg = 0; reg < 4; ++reg)
                C[(size_t)(row0 + reg) * N_DIM + col] = acc[m][n][reg] * s + bv;
        }
    }
}

// ---------- reduce block maxes + rolling-amax state update ----------
__global__ void state_kernel(const float* __restrict__ bmx, int nx,
                             const float* __restrict__ bmk, int nk,
                             const float* __restrict__ inHist,
                             const float* __restrict__ kHist,
                             float* __restrict__ tail) {
    __shared__ float red[8];
    const int t = threadIdx.x;
    float mx = 0.0f, mk = 0.0f;
    for (int i = t; i < nx; i += 256) mx = fmaxf(mx, bmx[i]);
    for (int i = t; i < nk; i += 256) mk = fmaxf(mk, bmk[i]);
    #pragma unroll
    for (int off = 32; off; off >>= 1) {
        mx = fmaxf(mx, __shfl_xor(mx, off));
        mk = fmaxf(mk, __shfl_xor(mk, off));
    }
    if ((t & 63) == 0) { red[t >> 6] = mx; red[4 + (t >> 6)] = mk; }
    __syncthreads();
    if (t == 0) {
        float amax_x = fmaxf(fmaxf(red[0], red[1]), fmaxf(red[2], red[3]));
        float amax_k = fmaxf(fmaxf(red[4], red[5]), fmaxf(red[6], red[7]));
        #pragma unroll
        for (int which = 0; which < 2; ++which) {
            const float* h = which ? kHist : inHist;
            float ac = which ? amax_k : amax_x;
            float m = fmaxf(0.0009765625f, ac);   // 2^-10
            tail[2 + which * 16 + 0] = ac;
            for (int i = 1; i < 16; ++i) {
                float v = h[i - 1];
                tail[2 + which * 16 + i] = v;
                m = fmaxf(m, v);
            }
            tail[which] = 1.1f * m / 448.0f;
        }
    }
}

extern "C" void kernel_launch(void* const* d_in, const int* in_sizes, int n_in,
                              void* d_out, int out_size, void* d_ws, size_t ws_size,
                              hipStream_t stream) {
    const float* x        = (const float*)d_in[0];
    const float* kern     = (const float*)d_in[1];
    const float* bias     = (const float*)d_in[2];
    const float* in_scale = (const float*)d_in[3];
    const float* k_scale  = (const float*)d_in[4];
    const float* in_hist  = (const float*)d_in[7];
    const float* k_hist   = (const float*)d_in[8];

    const int NBX = 2048;              // quant_x blocks
    const int NBK = 64 * 64;           // quant_kT blocks
    const size_t qx_bytes  = (size_t)M_DIM * K_DIM;       // 32 MiB
    const size_t qkT_bytes = (size_t)K_DIM * N_DIM;       // 16 MiB
    const size_t need = qx_bytes + qkT_bytes + (NBX + NBK) * sizeof(float);
    if (ws_size < need) return;  // fail visibly, no corruption

    uint8_t* qx  = (uint8_t*)d_ws;
    uint8_t* qkT = qx + qx_bytes;
    float*   bmx = (float*)(qkT + qkT_bytes);
    float*   bmk = bmx + NBX;
    float*   out = (float*)d_out;

    quant_x_kernel<<<NBX, 256, 0, stream>>>(x, qx, in_scale, bmx,
                                            (int)((size_t)M_DIM * K_DIM / 8));
    quant_kT_kernel<<<NBK, 256, 0, stream>>>(kern, qkT, k_scale, bmk);
    gemm_mx<<<(M_DIM / 128) * (N_DIM / 128), 256, 0, stream>>>(qx, qkT, bias,
                                                               in_scale, k_scale, out);
    state_kernel<<<1, 256, 0, stream>>>(bmx, NBX, bmk, NBK, in_hist, k_hist,
                                        out + (size_t)M_DIM * N_DIM);
}

// Round 4
// 210.839 us; speedup vs baseline: 3.0336x; 1.0623x over previous
//
#include <hip/hip_runtime.h>
#include <stdint.h>

#define M_DIM 8192
#define K_DIM 4096
#define N_DIM 4096

using f32x4 = __attribute__((ext_vector_type(4))) float;
using i32x4 = __attribute__((ext_vector_type(4))) int;
using i32x8 = __attribute__((ext_vector_type(8))) int;

#define UNIT_SCALE 0x7F7F7F7F   // 4x E8M0 exponent-127 bytes -> 2^0

// ---------- fp8 e4m3 packing (HW RNE conversion; inputs pre-clipped to +-448) ----------
__device__ inline uint32_t pk_fp8_x4(float a, float b, float c, float d) {
    int lo   = __builtin_amdgcn_cvt_pk_fp8_f32(a, b, 0, false);   // bytes 0,1
    int both = __builtin_amdgcn_cvt_pk_fp8_f32(c, d, lo, true);   // bytes 2,3
    return (uint32_t)both;
}

__device__ inline float clip448(float v) {
    return fminf(fmaxf(v, -448.0f), 448.0f);
}

__device__ inline void gload_lds16(const void* g, void* l) {
    __builtin_amdgcn_global_load_lds(
        (const __attribute__((address_space(1))) uint32_t*)g,
        (__attribute__((address_space(3))) uint32_t*)l, 16, 0, 0);
}

// K-permutation within each 128-byte K-block (for 16x16x128 scaled MFMA):
// orig k (c = k>>5, g = (k>>3)&3, j = k&7)  ->  stored p = g*32 + c*8 + j
// => a GEMM lane (g = lane>>4) reads its 32-byte fragment as logical units 2g, 2g+1.

// ---------- quantize x: f32 [M][K] -> e4m3 [M][K] (K-permuted), per-block amax ----------
__global__ void quant_x_kernel(const float* __restrict__ x, uint8_t* __restrict__ qx,
                               const float* __restrict__ scale_p, float* __restrict__ bm,
                               int n8) {
    __shared__ float red[4];
    const float inv = 1.0f / scale_p[0];
    float lmax = 0.0f;
    const float4* xv = (const float4*)x;
    const int stride = gridDim.x * blockDim.x;
    for (int u = blockIdx.x * blockDim.x + threadIdx.x; u < n8; u += stride) {
        float4 v0 = xv[2 * u];
        float4 v1 = xv[2 * u + 1];
        lmax = fmaxf(lmax, fmaxf(fmaxf(fabsf(v0.x), fabsf(v0.y)),
                                 fmaxf(fabsf(v0.z), fabsf(v0.w))));
        lmax = fmaxf(lmax, fmaxf(fmaxf(fabsf(v1.x), fabsf(v1.y)),
                                 fmaxf(fabsf(v1.z), fabsf(v1.w))));
        uint32_t w0 = pk_fp8_x4(clip448(v0.x * inv), clip448(v0.y * inv),
                                clip448(v0.z * inv), clip448(v0.w * inv));
        uint32_t w1 = pk_fp8_x4(clip448(v1.x * inv), clip448(v1.y * inv),
                                clip448(v1.z * inv), clip448(v1.w * inv));
        // permuted 8B destination within 128B block
        size_t b  = (size_t)(u >> 4);   // 128-byte block
        int   u8  = u & 15;             // orig 8B unit = c*4 + g
        int   c   = u8 >> 2, g = u8 & 3;
        uint2* dst = (uint2*)(qx + b * 128 + (size_t)(g * 4 + c) * 8);
        *dst = make_uint2(w0, w1);
    }
    #pragma unroll
    for (int off = 32; off; off >>= 1) lmax = fmaxf(lmax, __shfl_xor(lmax, off));
    if ((threadIdx.x & 63) == 0) red[threadIdx.x >> 6] = lmax;
    __syncthreads();
    if (threadIdx.x == 0)
        bm[blockIdx.x] = fmaxf(fmaxf(red[0], red[1]), fmaxf(red[2], red[3]));
}

// ---------- quantize kernel transposed: f32 [K][N] -> e4m3 [N][K] (K-permuted) ----------
__global__ void quant_kT_kernel(const float* __restrict__ kin, uint8_t* __restrict__ qkT,
                                const float* __restrict__ scale_p, float* __restrict__ bm) {
    __shared__ uint8_t sm[64 * 68];  // [k 0..63][n 0..63], pad 68
    __shared__ float red[4];
    const float inv = 1.0f / scale_p[0];
    const int t = threadIdx.x;
    const int bk = blockIdx.x & 63;   // K-tile index (64 tiles)
    const int bn = blockIdx.x >> 6;   // N-tile index (64 tiles)
    const int gk0 = bk * 64, gn0 = bn * 64;
    float lmax = 0.0f;

    #pragma unroll
    for (int it = 0; it < 4; ++it) {
        int k  = it * 16 + (t >> 4);
        int n4 = (t & 15) * 4;
        float4 v = *(const float4*)(kin + (size_t)(gk0 + k) * N_DIM + gn0 + n4);
        lmax = fmaxf(lmax, fmaxf(fmaxf(fabsf(v.x), fabsf(v.y)),
                                 fmaxf(fabsf(v.z), fabsf(v.w))));
        *(uint32_t*)(sm + k * 68 + n4) = pk_fp8_x4(clip448(v.x * inv), clip448(v.y * inv),
                                                   clip448(v.z * inv), clip448(v.w * inv));
    }
    __syncthreads();
    #pragma unroll
    for (int it = 0; it < 4; ++it) {
        int n  = it * 16 + (t >> 4);
        int k4 = (t & 15) * 4;                  // 0..60, multiple of 4
        uint32_t w = (uint32_t)sm[(k4 + 0) * 68 + n]
                   | ((uint32_t)sm[(k4 + 1) * 68 + n] << 8)
                   | ((uint32_t)sm[(k4 + 2) * 68 + n] << 16)
                   | ((uint32_t)sm[(k4 + 3) * 68 + n] << 24);
        int kk = (gk0 + k4);
        size_t b = (size_t)(kk >> 7);           // 128-byte block
        int  kp  = kk & 127;
        int  c   = kp >> 5, g = (kp >> 3) & 3, j = kp & 7;   // j in {0,4}
        int  p   = g * 32 + c * 8 + j;
        *(uint32_t*)(qkT + (size_t)(gn0 + n) * K_DIM + b * 128 + p) = w;
    }
    #pragma unroll
    for (int off = 32; off; off >>= 1) lmax = fmaxf(lmax, __shfl_xor(lmax, off));
    if ((t & 63) == 0) red[t >> 6] = lmax;
    __syncthreads();
    if (t == 0)
        bm[blockIdx.x] = fmaxf(fmaxf(red[0], red[1]), fmaxf(red[2], red[3]));
}

// ---------- MX-fp8 GEMM, 256x256 tile, 8-phase counted-vmcnt schedule ----------
// 8 waves (2M x 4N), per-wave 128x64 output = 8m x 4n fragments of 16x16.
// LDS: [dbuf][half] 16KB slots for A and B (128 KiB total), 16B-unit XOR swizzle
// (involution applied on pre-swizzled global source AND on the ds_read address).
// Per iteration (2 K-tiles): 8 phases; vmcnt(4) ONLY at phases 4 and 8.
// Slot rotation (iter i reads dbuf0=kt 2i, dbuf1=kt 2i+1):
//   p0: stage A[1] h0 (kt 2i+1)   p4: stage A[0] h0 (kt 2i+2)
//   p1: stage A[1] h1 (kt 2i+1)   p5: stage A[0] h1 (kt 2i+2)
//   p2: stage B[0] h0 (kt 2i+2)   p6: stage B[1] h0 (kt 2i+3)
//   p3: stage B[0] h1 (kt 2i+2)   p7: stage B[1] h1 (kt 2i+3)
// Every stage target's last ds_read is >=1 barrier in the past; vmcnt(4) at
// p3/p7 retires exactly the 4 half-units (8 loads FIFO) the next K-tile reads.

__device__ __forceinline__ i32x8 load_frag(const uint8_t* slot, int lrow, int g) {
    int s = lrow & 7;
    const uint8_t* p = slot + lrow * 128;
    i32x4 lo = *(const i32x4*)(p + (((g * 2 + 0) ^ s) * 16));
    i32x4 hi = *(const i32x4*)(p + (((g * 2 + 1) ^ s) * 16));
    i32x8 out;
    out[0] = lo[0]; out[1] = lo[1]; out[2] = lo[2]; out[3] = lo[3];
    out[4] = hi[0]; out[5] = hi[1]; out[6] = hi[2]; out[7] = hi[3];
    return out;
}

__global__ __launch_bounds__(512, 2) void gemm_mx8(
        const uint8_t* __restrict__ A,   // [M][K] e4m3, K-permuted per 128B block
        const uint8_t* __restrict__ Bt,  // [N][K] e4m3, K-permuted per 128B block
        const float* __restrict__ bias,
        const float* __restrict__ sIn, const float* __restrict__ sK,
        float* __restrict__ C) {
    __shared__ uint8_t smA[2][2][16384];
    __shared__ uint8_t smB[2][2][16384];

    const int tid = threadIdx.x;
    const int lane = tid & 63, wid = tid >> 6;
    const int wm = wid >> 2, wn = wid & 3;
    const int r = lane & 15, g = lane >> 4;

    // XCD-bijective swizzle: 512 blocks, 512 % 8 == 0
    const int swz = (blockIdx.x & 7) * 64 + (blockIdx.x >> 3);
    const int mt = swz >> 4, nt = swz & 15;           // 32 x 16 tiles
    const int gRow0 = mt * 256, gCol0 = nt * 256;

    // staging thread geometry: idx in [0,1024), 2 issues per thread per half-unit
    const int idx0 = tid, idx1 = tid + 512;
    const int row0 = idx0 >> 3, row1 = idx1 >> 3;     // 0..63 / 64..127
    const size_t off0 = (size_t)row0 * K_DIM + (((idx0 & 7) ^ (row0 & 7)) * 16);
    const size_t off1 = (size_t)row1 * K_DIM + (((idx1 & 7) ^ (row1 & 7)) * 16);
    const int dst0 = idx0 * 16, dst1 = idx1 * 16;

    const uint8_t* Abase = A  + (size_t)gRow0 * K_DIM;
    const uint8_t* Bbase = Bt + (size_t)gCol0 * K_DIM;

#define STAGE_A(d, h, kt) do {                                                   \
    const uint8_t* s_ = Abase + (size_t)(h) * (128 * (size_t)K_DIM)              \
                              + (size_t)(kt) * 128;                              \
    gload_lds16(s_ + off0, &smA[d][h][dst0]);                                    \
    gload_lds16(s_ + off1, &smA[d][h][dst1]); } while (0)
#define STAGE_B(d, h, kt) do {                                                   \
    const uint8_t* s_ = Bbase + (size_t)(h) * (128 * (size_t)K_DIM)              \
                              + (size_t)(kt) * 128;                              \
    gload_lds16(s_ + off0, &smB[d][h][dst0]);                                    \
    gload_lds16(s_ + off1, &smB[d][h][dst1]); } while (0)

    f32x4 acc[8][4] = {};

    // prologue: B-K0, A-K0, B-K1 (6 half-units, 12 loads); keep B-K1 in flight
    STAGE_B(0, 0, 0); STAGE_B(0, 1, 0);
    STAGE_A(0, 0, 0); STAGE_A(0, 1, 0);
    STAGE_B(1, 0, 1); STAGE_B(1, 1, 1);
    asm volatile("s_waitcnt vmcnt(4)" ::: "memory");
    __builtin_amdgcn_s_barrier();

    const int aHalf = wm;
    const int bHalf = wn >> 1;
    const int bRow  = (wn & 1) * 64;

    i32x8 bf[4];

#define PHASE(D, Q, STAGE, VM) do {                                              \
    if ((Q) == 0) {                                                              \
        bf[0] = load_frag(&smB[D][bHalf][0], bRow + 0 * 16 + r, g);              \
        bf[1] = load_frag(&smB[D][bHalf][0], bRow + 1 * 16 + r, g);              \
        bf[2] = load_frag(&smB[D][bHalf][0], bRow + 2 * 16 + r, g);              \
        bf[3] = load_frag(&smB[D][bHalf][0], bRow + 3 * 16 + r, g);              \
    }                                                                            \
    i32x8 a0 = load_frag(&smA[D][aHalf][0], (2 * (Q) + 0) * 16 + r, g);          \
    i32x8 a1 = load_frag(&smA[D][aHalf][0], (2 * (Q) + 1) * 16 + r, g);          \
    STAGE;                                                                       \
    __builtin_amdgcn_s_barrier();                                                \
    asm volatile("s_waitcnt lgkmcnt(0)" ::: "memory");                           \
    __builtin_amdgcn_sched_barrier(0);                                           \
    __builtin_amdgcn_s_setprio(1);                                               \
    _Pragma("unroll")                                                            \
    for (int nn = 0; nn < 4; ++nn) {                                             \
        acc[2 * (Q) + 0][nn] = __builtin_amdgcn_mfma_scale_f32_16x16x128_f8f6f4( \
            a0, bf[nn], acc[2 * (Q) + 0][nn], 0, 0, 0, UNIT_SCALE, 0, UNIT_SCALE); \
        acc[2 * (Q) + 1][nn] = __builtin_amdgcn_mfma_scale_f32_16x16x128_f8f6f4( \
            a1, bf[nn], acc[2 * (Q) + 1][nn], 0, 0, 0, UNIT_SCALE, 0, UNIT_SCALE); \
    }                                                                            \
    __builtin_amdgcn_s_setprio(0);                                               \
    if (VM) asm volatile("s_waitcnt vmcnt(4)" ::: "memory");                     \
    __builtin_amdgcn_s_barrier();                                                \
} while (0)

    for (int i = 0; i < K_DIM / 256; ++i) {          // 16 iterations, 2 K-tiles each
        const int kt1  = 2 * i + 1;
        const int ktn0 = (2 * i + 2) & 31;           // wraps harmlessly on last iter
        const int ktn1 = (2 * i + 3) & 31;
        PHASE(0, 0, STAGE_A(1, 0, kt1),  0);
        PHASE(0, 1, STAGE_A(1, 1, kt1),  0);
        PHASE(0, 2, STAGE_B(0, 0, ktn0), 0);
        PHASE(0, 3, STAGE_B(0, 1, ktn0), 1);
        PHASE(1, 0, STAGE_A(0, 0, ktn0), 0);
        PHASE(1, 1, STAGE_A(0, 1, ktn0), 0);
        PHASE(1, 2, STAGE_B(1, 0, ktn1), 0);
        PHASE(1, 3, STAGE_B(1, 1, ktn1), 1);
    }

    const float s = sIn[0] * sK[0];
    #pragma unroll
    for (int n = 0; n < 4; ++n) {
        const int col = gCol0 + wn * 64 + n * 16 + r;
        const float bv = bias[col];
        #pragma unroll
        for (int m = 0; m < 8; ++m) {
            const int rw = gRow0 + wm * 128 + m * 16 + g * 4;
            #pragma unroll
            for (int reg = 0; reg < 4; ++reg)
                C[(size_t)(rw + reg) * N_DIM + col] = acc[m][n][reg] * s + bv;
        }
    }
#undef PHASE
#undef STAGE_A
#undef STAGE_B
}

// ---------- reduce block maxes + rolling-amax state update ----------
__global__ void state_kernel(const float* __restrict__ bmx, int nx,
                             const float* __restrict__ bmk, int nk,
                             const float* __restrict__ inHist,
                             const float* __restrict__ kHist,
                             float* __restrict__ tail) {
    __shared__ float red[8];
    const int t = threadIdx.x;
    float mx = 0.0f, mk = 0.0f;
    for (int i = t; i < nx; i += 256) mx = fmaxf(mx, bmx[i]);
    for (int i = t; i < nk; i += 256) mk = fmaxf(mk, bmk[i]);
    #pragma unroll
    for (int off = 32; off; off >>= 1) {
        mx = fmaxf(mx, __shfl_xor(mx, off));
        mk = fmaxf(mk, __shfl_xor(mk, off));
    }
    if ((t & 63) == 0) { red[t >> 6] = mx; red[4 + (t >> 6)] = mk; }
    __syncthreads();
    if (t == 0) {
        float amax_x = fmaxf(fmaxf(red[0], red[1]), fmaxf(red[2], red[3]));
        float amax_k = fmaxf(fmaxf(red[4], red[5]), fmaxf(red[6], red[7]));
        #pragma unroll
        for (int which = 0; which < 2; ++which) {
            const float* h = which ? kHist : inHist;
            float ac = which ? amax_k : amax_x;
            float m = fmaxf(0.0009765625f, ac);   // 2^-10
            tail[2 + which * 16 + 0] = ac;
            for (int i = 1; i < 16; ++i) {
                float v = h[i - 1];
                tail[2 + which * 16 + i] = v;
                m = fmaxf(m, v);
            }
            tail[which] = 1.1f * m / 448.0f;
        }
    }
}

extern "C" void kernel_launch(void* const* d_in, const int* in_sizes, int n_in,
                              void* d_out, int out_size, void* d_ws, size_t ws_size,
                              hipStream_t stream) {
    const float* x        = (const float*)d_in[0];
    const float* kern     = (const float*)d_in[1];
    const float* bias     = (const float*)d_in[2];
    const float* in_scale = (const float*)d_in[3];
    const float* k_scale  = (const float*)d_in[4];
    const float* in_hist  = (const float*)d_in[7];
    const float* k_hist   = (const float*)d_in[8];

    const int NBX = 2048;              // quant_x blocks
    const int NBK = 64 * 64;           // quant_kT blocks
    const size_t qx_bytes  = (size_t)M_DIM * K_DIM;       // 32 MiB
    const size_t qkT_bytes = (size_t)K_DIM * N_DIM;       // 16 MiB
    const size_t need = qx_bytes + qkT_bytes + (NBX + NBK) * sizeof(float);
    if (ws_size < need) return;  // fail visibly, no corruption

    uint8_t* qx  = (uint8_t*)d_ws;
    uint8_t* qkT = qx + qx_bytes;
    float*   bmx = (float*)(qkT + qkT_bytes);
    float*   bmk = bmx + NBX;
    float*   out = (float*)d_out;

    quant_x_kernel<<<NBX, 256, 0, stream>>>(x, qx, in_scale, bmx,
                                            (int)((size_t)M_DIM * K_DIM / 8));
    quant_kT_kernel<<<NBK, 256, 0, stream>>>(kern, qkT, k_scale, bmk);
    gemm_mx8<<<(M_DIM / 256) * (N_DIM / 256), 512, 0, stream>>>(qx, qkT, bias,
                                                                in_scale, k_scale, out);
    state_kernel<<<1, 256, 0, stream>>>(bmx, NBX, bmk, NBK, in_hist, k_hist,
                                        out + (size_t)M_DIM * N_DIM);
}

// Round 5
// 201.923 us; speedup vs baseline: 3.1675x; 1.0442x over previous
//
#include <hip/hip_runtime.h>
#include <stdint.h>

#define M_DIM 8192
#define K_DIM 4096
#define N_DIM 4096

using f32x4 = __attribute__((ext_vector_type(4))) float;
using i32x4 = __attribute__((ext_vector_type(4))) int;
using i32x8 = __attribute__((ext_vector_type(8))) int;

#define UNIT_SCALE 0x7F7F7F7F   // 4x E8M0 exponent-127 bytes -> 2^0

// ---------- fp8 e4m3 packing (HW RNE conversion; inputs pre-clipped to +-448) ----------
__device__ inline uint32_t pk_fp8_x4(float a, float b, float c, float d) {
    int lo   = __builtin_amdgcn_cvt_pk_fp8_f32(a, b, 0, false);   // bytes 0,1
    int both = __builtin_amdgcn_cvt_pk_fp8_f32(c, d, lo, true);   // bytes 2,3
    return (uint32_t)both;
}

__device__ inline float clip448(float v) {
    return fminf(fmaxf(v, -448.0f), 448.0f);
}

__device__ inline void gload_lds16(const void* g, void* l) {
    __builtin_amdgcn_global_load_lds(
        (const __attribute__((address_space(1))) uint32_t*)g,
        (__attribute__((address_space(3))) uint32_t*)l, 16, 0, 0);
}

// K-permutation within each 128-byte K-block (for 16x16x128 scaled MFMA):
// orig k (c = k>>5, g = (k>>3)&3, j = k&7)  ->  stored p = g*32 + c*8 + j
// => a GEMM lane (g = lane>>4) reads its 32-byte fragment as logical units 2g, 2g+1.

// ---------- quantize x: f32 [M][K] -> e4m3 [M][K] (K-permuted), per-block amax ----------
__global__ void quant_x_kernel(const float* __restrict__ x, uint8_t* __restrict__ qx,
                               const float* __restrict__ scale_p, float* __restrict__ bm,
                               int n8) {
    __shared__ float red[4];
    const float inv = 1.0f / scale_p[0];
    float lmax = 0.0f;
    const float4* xv = (const float4*)x;
    const int stride = gridDim.x * blockDim.x;
    for (int u = blockIdx.x * blockDim.x + threadIdx.x; u < n8; u += stride) {
        float4 v0 = xv[2 * u];
        float4 v1 = xv[2 * u + 1];
        lmax = fmaxf(lmax, fmaxf(fmaxf(fabsf(v0.x), fabsf(v0.y)),
                                 fmaxf(fabsf(v0.z), fabsf(v0.w))));
        lmax = fmaxf(lmax, fmaxf(fmaxf(fabsf(v1.x), fabsf(v1.y)),
                                 fmaxf(fabsf(v1.z), fabsf(v1.w))));
        uint32_t w0 = pk_fp8_x4(clip448(v0.x * inv), clip448(v0.y * inv),
                                clip448(v0.z * inv), clip448(v0.w * inv));
        uint32_t w1 = pk_fp8_x4(clip448(v1.x * inv), clip448(v1.y * inv),
                                clip448(v1.z * inv), clip448(v1.w * inv));
        // permuted 8B destination within 128B block
        size_t b  = (size_t)(u >> 4);   // 128-byte block
        int   u8  = u & 15;             // orig 8B unit = c*4 + g
        int   c   = u8 >> 2, g = u8 & 3;
        uint2* dst = (uint2*)(qx + b * 128 + (size_t)(g * 4 + c) * 8);
        *dst = make_uint2(w0, w1);
    }
    #pragma unroll
    for (int off = 32; off; off >>= 1) lmax = fmaxf(lmax, __shfl_xor(lmax, off));
    if ((threadIdx.x & 63) == 0) red[threadIdx.x >> 6] = lmax;
    __syncthreads();
    if (threadIdx.x == 0)
        bm[blockIdx.x] = fmaxf(fmaxf(red[0], red[1]), fmaxf(red[2], red[3]));
}

// ---------- quantize kernel transposed: f32 [K][N] -> e4m3 [N][K] (K-permuted) ----------
__global__ void quant_kT_kernel(const float* __restrict__ kin, uint8_t* __restrict__ qkT,
                                const float* __restrict__ scale_p, float* __restrict__ bm) {
    __shared__ uint8_t sm[64 * 68];  // [k 0..63][n 0..63], pad 68
    __shared__ float red[4];
    const float inv = 1.0f / scale_p[0];
    const int t = threadIdx.x;
    const int bk = blockIdx.x & 63;   // K-tile index (64 tiles)
    const int bn = blockIdx.x >> 6;   // N-tile index (64 tiles)
    const int gk0 = bk * 64, gn0 = bn * 64;
    float lmax = 0.0f;

    #pragma unroll
    for (int it = 0; it < 4; ++it) {
        int k  = it * 16 + (t >> 4);
        int n4 = (t & 15) * 4;
        float4 v = *(const float4*)(kin + (size_t)(gk0 + k) * N_DIM + gn0 + n4);
        lmax = fmaxf(lmax, fmaxf(fmaxf(fabsf(v.x), fabsf(v.y)),
                                 fmaxf(fabsf(v.z), fabsf(v.w))));
        *(uint32_t*)(sm + k * 68 + n4) = pk_fp8_x4(clip448(v.x * inv), clip448(v.y * inv),
                                                   clip448(v.z * inv), clip448(v.w * inv));
    }
    __syncthreads();
    #pragma unroll
    for (int it = 0; it < 4; ++it) {
        int n  = it * 16 + (t >> 4);
        int k4 = (t & 15) * 4;                  // 0..60, multiple of 4
        uint32_t w = (uint32_t)sm[(k4 + 0) * 68 + n]
                   | ((uint32_t)sm[(k4 + 1) * 68 + n] << 8)
                   | ((uint32_t)sm[(k4 + 2) * 68 + n] << 16)
                   | ((uint32_t)sm[(k4 + 3) * 68 + n] << 24);
        int kk = (gk0 + k4);
        size_t b = (size_t)(kk >> 7);           // 128-byte block
        int  kp  = kk & 127;
        int  c   = kp >> 5, g = (kp >> 3) & 3, j = kp & 7;   // j in {0,4}
        int  p   = g * 32 + c * 8 + j;
        *(uint32_t*)(qkT + (size_t)(gn0 + n) * K_DIM + b * 128 + p) = w;
    }
    #pragma unroll
    for (int off = 32; off; off >>= 1) lmax = fmaxf(lmax, __shfl_xor(lmax, off));
    if ((t & 63) == 0) red[t >> 6] = lmax;
    __syncthreads();
    if (t == 0)
        bm[blockIdx.x] = fmaxf(fmaxf(red[0], red[1]), fmaxf(red[2], red[3]));
}

// ---------- MX-fp8 GEMM, 256x256 tile, 8-phase counted-vmcnt + counted-lgkm ----------
// 8 waves (2M x 4N), per-wave 128x64 output = 8m x 4n fragments of 16x16.
// LDS half-slot (128 rows x 128B) is SUBTILED: [rowgrp=row>>4][khalf=lu>>2][r=row&15][u4]
//   phys = rowgrp*2048 + khalf*1024 + r*64 + ((lu&3) ^ ((r>>1)&3))*16
// Within-subtile row stride 64B puts row bit0 into bank bit4; the u4^=(r>>1)&3
// XOR puts row bits 1-2 into bank bits 3:2 -> a frag read's 16 rows cover all
// 32 banks with exactly 2 lanes/bank (2-way = free, m136).
// ds_read groups are order-pinned with sched_barrier(0); counted lgkmcnt waits
// interleave with the MFMAs so LDS latency+BW overlap the matrix pipe.
// vmcnt(4) only at phases 4 and 8 (same rotation as round 4).

__device__ __forceinline__ i32x8 load_frag(const uint8_t* slot, int lrow, int g) {
    const int rg = lrow >> 4, rr = lrow & 15;
    const int sx = (rr >> 1) & 3;
    const uint8_t* p = slot + rg * 2048 + rr * 64;
    const int lu0 = 2 * g, lu1 = 2 * g + 1;
    i32x4 lo = *(const i32x4*)(p + (lu0 >> 2) * 1024 + (((lu0 & 3) ^ sx) * 16));
    i32x4 hi = *(const i32x4*)(p + (lu1 >> 2) * 1024 + (((lu1 & 3) ^ sx) * 16));
    i32x8 out;
    out[0] = lo[0]; out[1] = lo[1]; out[2] = lo[2]; out[3] = lo[3];
    out[4] = hi[0]; out[5] = hi[1]; out[6] = hi[2]; out[7] = hi[3];
    return out;
}

#define SB __builtin_amdgcn_sched_barrier(0)
#define WAITL(N) asm volatile("s_waitcnt lgkmcnt(" #N ")" ::: "memory")
#define MM(qq, nn, areg)                                                        \
    acc[qq][nn] = __builtin_amdgcn_mfma_scale_f32_16x16x128_f8f6f4(             \
        areg, bf[nn], acc[qq][nn], 0, 0, 0, UNIT_SCALE, 0, UNIT_SCALE)

__global__ __launch_bounds__(512, 2) void gemm_mx8(
        const uint8_t* __restrict__ A,   // [M][K] e4m3, K-permuted per 128B block
        const uint8_t* __restrict__ Bt,  // [N][K] e4m3, K-permuted per 128B block
        const float* __restrict__ bias,
        const float* __restrict__ sIn, const float* __restrict__ sK,
        float* __restrict__ C) {
    __shared__ uint8_t smA[2][2][16384];
    __shared__ uint8_t smB[2][2][16384];

    const int tid = threadIdx.x;
    const int lane = tid & 63, wid = tid >> 6;
    const int wm = wid >> 2, wn = wid & 3;
    const int r = lane & 15, g = lane >> 4;

    // XCD-bijective swizzle: 512 blocks, 512 % 8 == 0
    const int swz = (blockIdx.x & 7) * 64 + (blockIdx.x >> 3);
    const int mt = swz >> 4, nt = swz & 15;           // 32 x 16 tiles
    const int gRow0 = mt * 256, gCol0 = nt * 256;

    // staging geometry: idx in [0,1024); linear LDS dest idx*16.
    // idx -> rowgrp=idx>>7, khalf=(idx>>6)&1, rr=(idx>>2)&15, pu4=idx&3
    // source logical: row = rowgrp*16+rr ; lu = khalf*4 + (pu4 ^ ((rr>>1)&3))
    const int idx0 = tid, idx1 = tid + 512;
    const int rr0 = (idx0 >> 2) & 15, rr1 = (idx1 >> 2) & 15;
    const int row0 = (idx0 >> 7) * 16 + rr0;
    const int row1 = (idx1 >> 7) * 16 + rr1;
    const int lu0 = ((idx0 >> 6) & 1) * 4 + ((idx0 & 3) ^ ((rr0 >> 1) & 3));
    const int lu1 = ((idx1 >> 6) & 1) * 4 + ((idx1 & 3) ^ ((rr1 >> 1) & 3));
    const size_t off0 = (size_t)row0 * K_DIM + lu0 * 16;
    const size_t off1 = (size_t)row1 * K_DIM + lu1 * 16;
    const int dst0 = idx0 * 16, dst1 = idx1 * 16;

    const uint8_t* Abase = A  + (size_t)gRow0 * K_DIM;
    const uint8_t* Bbase = Bt + (size_t)gCol0 * K_DIM;

#define STAGE_A(d, h, kt) do {                                                   \
    const uint8_t* s_ = Abase + (size_t)(h) * (128 * (size_t)K_DIM)              \
                              + (size_t)(kt) * 128;                              \
    gload_lds16(s_ + off0, &smA[d][h][dst0]);                                    \
    gload_lds16(s_ + off1, &smA[d][h][dst1]); } while (0)
#define STAGE_B(d, h, kt) do {                                                   \
    const uint8_t* s_ = Bbase + (size_t)(h) * (128 * (size_t)K_DIM)              \
                              + (size_t)(kt) * 128;                              \
    gload_lds16(s_ + off0, &smB[d][h][dst0]);                                    \
    gload_lds16(s_ + off1, &smB[d][h][dst1]); } while (0)

    f32x4 acc[8][4] = {};

    // prologue: B-K0, A-K0, B-K1 (6 half-units, 12 loads); keep B-K1 in flight
    STAGE_B(0, 0, 0); STAGE_B(0, 1, 0);
    STAGE_A(0, 0, 0); STAGE_A(0, 1, 0);
    STAGE_B(1, 0, 1); STAGE_B(1, 1, 1);
    asm volatile("s_waitcnt vmcnt(4)" ::: "memory");
    __builtin_amdgcn_s_barrier();

    const int aHalf = wm;
    const int bHalf = wn >> 1;
    const int bRow  = (wn & 1) * 64;

    i32x8 bf[4];

#define PHASE(D, Q, STAGE, VM) do {                                              \
    i32x8 a0, a1;                                                                \
    if ((Q) == 0) {                                                              \
        a0    = load_frag(&smA[D][aHalf][0], 0 * 16 + r, g);            SB;      \
        bf[0] = load_frag(&smB[D][bHalf][0], bRow + 0 * 16 + r, g);     SB;      \
        a1    = load_frag(&smA[D][aHalf][0], 1 * 16 + r, g);            SB;      \
        bf[1] = load_frag(&smB[D][bHalf][0], bRow + 1 * 16 + r, g);     SB;      \
        bf[2] = load_frag(&smB[D][bHalf][0], bRow + 2 * 16 + r, g);     SB;      \
        bf[3] = load_frag(&smB[D][bHalf][0], bRow + 3 * 16 + r, g);     SB;      \
    } else {                                                                     \
        a0 = load_frag(&smA[D][aHalf][0], (2 * (Q) + 0) * 16 + r, g);   SB;      \
        a1 = load_frag(&smA[D][aHalf][0], (2 * (Q) + 1) * 16 + r, g);   SB;      \
    }                                                                            \
    STAGE;                                                                       \
    __builtin_amdgcn_s_barrier();                                                \
    __builtin_amdgcn_s_setprio(1);                                               \
    if ((Q) == 0) {                                                              \
        WAITL(8); SB; MM(0, 0, a0);                                              \
        WAITL(6); SB; MM(1, 0, a1);                                              \
        WAITL(4); SB; MM(0, 1, a0); MM(1, 1, a1);                                \
        WAITL(2); SB; MM(0, 2, a0); MM(1, 2, a1);                                \
        WAITL(0); SB; MM(0, 3, a0); MM(1, 3, a1);                                \
    } else {                                                                     \
        WAITL(2); SB;                                                            \
        MM(2*(Q)+0, 0, a0); MM(2*(Q)+0, 1, a0);                                  \
        MM(2*(Q)+0, 2, a0); MM(2*(Q)+0, 3, a0);                                  \
        WAITL(0); SB;                                                            \
        MM(2*(Q)+1, 0, a1); MM(2*(Q)+1, 1, a1);                                  \
        MM(2*(Q)+1, 2, a1); MM(2*(Q)+1, 3, a1);                                  \
    }                                                                            \
    __builtin_amdgcn_s_setprio(0);                                               \
    if (VM) asm volatile("s_waitcnt vmcnt(4)" ::: "memory");                     \
    __builtin_amdgcn_s_barrier();                                                \
} while (0)

    for (int i = 0; i < K_DIM / 256; ++i) {          // 16 iterations, 2 K-tiles each
        const int kt1  = 2 * i + 1;
        const int ktn0 = (2 * i + 2) & 31;           // wraps harmlessly on last iter
        const int ktn1 = (2 * i + 3) & 31;
        PHASE(0, 0, STAGE_A(1, 0, kt1),  0);
        PHASE(0, 1, STAGE_A(1, 1, kt1),  0);
        PHASE(0, 2, STAGE_B(0, 0, ktn0), 0);
        PHASE(0, 3, STAGE_B(0, 1, ktn0), 1);
        PHASE(1, 0, STAGE_A(0, 0, ktn0), 0);
        PHASE(1, 1, STAGE_A(0, 1, ktn0), 0);
        PHASE(1, 2, STAGE_B(1, 0, ktn1), 0);
        PHASE(1, 3, STAGE_B(1, 1, ktn1), 1);
    }

    const float s = sIn[0] * sK[0];
    #pragma unroll
    for (int n = 0; n < 4; ++n) {
        const int col = gCol0 + wn * 64 + n * 16 + r;
        const float bv = bias[col];
        #pragma unroll
        for (int m = 0; m < 8; ++m) {
            const int rw = gRow0 + wm * 128 + m * 16 + g * 4;
            #pragma unroll
            for (int reg = 0; reg < 4; ++reg)
                C[(size_t)(rw + reg) * N_DIM + col] = acc[m][n][reg] * s + bv;
        }
    }
#undef PHASE
#undef STAGE_A
#undef STAGE_B
}

// ---------- reduce block maxes + rolling-amax state update ----------
__global__ void state_kernel(const float* __restrict__ bmx, int nx,
                             const float* __restrict__ bmk, int nk,
                             const float* __restrict__ inHist,
                             const float* __restrict__ kHist,
                             float* __restrict__ tail) {
    __shared__ float red[8];
    const int t = threadIdx.x;
    float mx = 0.0f, mk = 0.0f;
    for (int i = t; i < nx; i += 256) mx = fmaxf(mx, bmx[i]);
    for (int i = t; i < nk; i += 256) mk = fmaxf(mk, bmk[i]);
    #pragma unroll
    for (int off = 32; off; off >>= 1) {
        mx = fmaxf(mx, __shfl_xor(mx, off));
        mk = fmaxf(mk, __shfl_xor(mk, off));
    }
    if ((t & 63) == 0) { red[t >> 6] = mx; red[4 + (t >> 6)] = mk; }
    __syncthreads();
    if (t == 0) {
        float amax_x = fmaxf(fmaxf(red[0], red[1]), fmaxf(red[2], red[3]));
        float amax_k = fmaxf(fmaxf(red[4], red[5]), fmaxf(red[6], red[7]));
        #pragma unroll
        for (int which = 0; which < 2; ++which) {
            const float* h = which ? kHist : inHist;
            float ac = which ? amax_k : amax_x;
            float m = fmaxf(0.0009765625f, ac);   // 2^-10
            tail[2 + which * 16 + 0] = ac;
            for (int i = 1; i < 16; ++i) {
                float v = h[i - 1];
                tail[2 + which * 16 + i] = v;
                m = fmaxf(m, v);
            }
            tail[which] = 1.1f * m / 448.0f;
        }
    }
}

extern "C" void kernel_launch(void* const* d_in, const int* in_sizes, int n_in,
                              void* d_out, int out_size, void* d_ws, size_t ws_size,
                              hipStream_t stream) {
    const float* x        = (const float*)d_in[0];
    const float* kern     = (const float*)d_in[1];
    const float* bias     = (const float*)d_in[2];
    const float* in_scale = (const float*)d_in[3];
    const float* k_scale  = (const float*)d_in[4];
    const float* in_hist  = (const float*)d_in[7];
    const float* k_hist   = (const float*)d_in[8];

    const int NBX = 2048;              // quant_x blocks
    const int NBK = 64 * 64;           // quant_kT blocks
    const size_t qx_bytes  = (size_t)M_DIM * K_DIM;       // 32 MiB
    const size_t qkT_bytes = (size_t)K_DIM * N_DIM;       // 16 MiB
    const size_t need = qx_bytes + qkT_bytes + (NBX + NBK) * sizeof(float);
    if (ws_size < need) return;  // fail visibly, no corruption

    uint8_t* qx  = (uint8_t*)d_ws;
    uint8_t* qkT = qx + qx_bytes;
    float*   bmx = (float*)(qkT + qkT_bytes);
    float*   bmk = bmx + NBX;
    float*   out = (float*)d_out;

    quant_x_kernel<<<NBX, 256, 0, stream>>>(x, qx, in_scale, bmx,
                                            (int)((size_t)M_DIM * K_DIM / 8));
    quant_kT_kernel<<<NBK, 256, 0, stream>>>(kern, qkT, k_scale, bmk);
    gemm_mx8<<<(M_DIM / 256) * (N_DIM / 256), 512, 0, stream>>>(qx, qkT, bias,
                                                                in_scale, k_scale, out);
    state_kernel<<<1, 256, 0, stream>>>(bmx, NBX, bmk, NBK, in_hist, k_hist,
                                        out + (size_t)M_DIM * N_DIM);
}